// Round 7
// baseline (3700.074 us; speedup 1.0000x reference)
//
#include <hip/hip_runtime.h>
#include <hip/hip_bf16.h>

#define T_STEPS 512
#define HID 512
#define EMB_D 300
#define BATCH 64
#define NCLS 1000

typedef __attribute__((ext_vector_type(4))) float f32x4;
typedef __attribute__((ext_vector_type(8))) short bf16x8;
typedef __attribute__((ext_vector_type(4))) unsigned int u32x4;
typedef __attribute__((ext_vector_type(2))) unsigned int u32x2;

union FragU { u32x4 u; bf16x8 b; };

__device__ __forceinline__ unsigned cvtpk(float lo, float hi) {
  unsigned r;
  asm("v_cvt_pk_bf16_f32 %0, %1, %2" : "=v"(r) : "v"(lo), "v"(hi));
  return r;
}

__device__ __forceinline__ bf16x8 pack8(f32x4 lo, f32x4 hi) {
  FragU u;
  u.u = (u32x4){cvtpk(lo.x, lo.y), cvtpk(lo.z, lo.w), cvtpk(hi.x, hi.y), cvtpk(hi.z, hi.w)};
  return u.b;
}

// tanh(x) = 1 - 2/(e+1), e = 2^(2*log2e*x). No clamp needed: e->0 gives -1, e->inf gives 1.
__device__ __forceinline__ float tanh_fast(float x) {
  float e = __builtin_amdgcn_exp2f(x * 2.8853900817779268f);
  return fmaf(-2.0f, __builtin_amdgcn_rcpf(e + 1.0f), 1.0f);
}

__device__ __forceinline__ float bf16lo(unsigned u) { return __uint_as_float(u << 16); }
__device__ __forceinline__ float bf16hi(unsigned u) { return __uint_as_float(u & 0xffff0000u); }

#define MFMA16(A, B, C) __builtin_amdgcn_mfma_f32_16x16x32_bf16(A, B, C, 0, 0, 0)

// ---------------------------------------------------------------------------
// K0: pack W_hh (f32) -> bf16 A-operand fragments.
// wpack[wv 8][tile 4][kk 16][lane 64][e 8] = Whh[wv*64+tile*16+(lane&15)][kk*32+(lane>>4)*8+e]
// ---------------------------------------------------------------------------
__global__ __launch_bounds__(256) void k0_pack(const float* __restrict__ Whh,
                                               unsigned short* __restrict__ wpack) {
  const int idx = blockIdx.x * 256 + threadIdx.x;  // 0..32767 lane-frags
  const int lane = idx & 63;
  const int kk = (idx >> 6) & 15;
  const int tw = (idx >> 10) & 3;
  const int wv = idx >> 12;
  const int c = lane & 15, g = lane >> 4;
  const int i = wv * 64 + tw * 16 + c;
  const int j = kk * 32 + g * 8;
  f32x4 lo = *(const f32x4*)(Whh + (size_t)i * HID + j);
  f32x4 hi = *(const f32x4*)(Whh + (size_t)i * HID + j + 4);
  *(bf16x8*)(wpack + (size_t)idx * 8) = pack8(lo, hi);
}

// ---------------------------------------------------------------------------
// K12 fused: blocks [0, rnn_blocks) = persistent RNN consumers (wg = blockIdx);
// blocks >= rnn_blocks = K1 producers (t = blockIdx - rnn_blocks) that compute
// xp[t] = emb[x[:,t]] . W_ih^T + b_ih + b_hh (tile-packed bf16) and post flag[t].
//
// RNN: 4 WGs x 512 thr (8 waves), WG owns 16 batch rows, wave owns 64 n-cols.
// All 64 W_hh fragments register-resident (launch_bounds(512,2) -> 1024-reg
// budget). h double-buffered in LDS in FRAGMENT layout hfrag[kk][lane][8]
// (conflict-free lane*16B reads, conflict-free 8B writes). Per step:
// phaseA MFMA(acc0,acc1) -> tanh0 -> phaseB MFMA(acc2,acc3) -> tanh1..3 ->
// barrier. xq loaded after flag[t] confirmed; flag[t+1] prefetched mid-step.
// ---------------------------------------------------------------------------
__global__ __launch_bounds__(512, 2) void k12_fused(
    const int* __restrict__ x, const float* __restrict__ emb,
    const float* __restrict__ Wih, const float* __restrict__ bih,
    const float* __restrict__ bhh, unsigned short* __restrict__ xp,
    const unsigned short* __restrict__ wpack, float* __restrict__ hT,
    unsigned* flags, int rnn_blocks, int spin) {
  __shared__ __align__(16) char SM[42240];   // max(k1: 256+41984, rnn: 32768)
  const int tid = threadIdx.x;

  if ((int)blockIdx.x < rnn_blocks) {
    // ===================== RNN role =====================
    const int wg = blockIdx.x;
    const int wv = tid >> 6, lane = tid & 63;
    const int c = lane & 15, g = lane >> 4;
    unsigned short* hfrag = (unsigned short*)SM;   // [2][16 kk][64 lane][8] shorts

    // all 4 weight tiles -> registers (64 frags = 256 regs; budget 1024)
    const unsigned short* wp = wpack + (size_t)wv * 32768 + (size_t)lane * 8;
    bf16x8 wr0[16], wr1[16], wr2[16], wr3[16];
    #pragma unroll
    for (int kk = 0; kk < 16; ++kk) {
      wr0[kk] = *(const bf16x8*)(wp + (size_t)kk * 512);
      wr1[kk] = *(const bf16x8*)(wp + (size_t)(16 + kk) * 512);
      wr2[kk] = *(const bf16x8*)(wp + (size_t)(32 + kk) * 512);
      wr3[kk] = *(const bf16x8*)(wp + (size_t)(48 + kk) * 512);
    }

    for (int i = tid; i < 8192; i += 512) ((unsigned*)hfrag)[i] = 0;  // h0 = 0 (both bufs)
    __syncthreads();

    // xp offsets: element (t, a=wg, nt=wv*4+tau, lane) at
    //   ((t*4+a)*32+nt)*256 + lane*4 shorts
    const unsigned short* xpb = xp + (size_t)wg * 8192 + (size_t)wv * 1024 + (size_t)lane * 4;
    const int kkw = wv * 2;

    unsigned fn = 1u;
    if (spin) fn = __hip_atomic_load(&flags[0], __ATOMIC_ACQUIRE, __HIP_MEMORY_SCOPE_AGENT);
    int cur = 0;

    #pragma unroll 1
    for (int t = 0; t < T_STEPS; ++t) {
      if (spin) {
        while (fn != 1u)
          fn = __hip_atomic_load(&flags[t], __ATOMIC_ACQUIRE, __HIP_MEMORY_SCOPE_AGENT);
      }
      const unsigned short* xq_p = xpb + (size_t)t * 32768;
      u32x2 xq0 = *(const u32x2*)(xq_p);
      u32x2 xq1 = *(const u32x2*)(xq_p + 256);
      u32x2 xq2 = *(const u32x2*)(xq_p + 512);
      u32x2 xq3 = *(const u32x2*)(xq_p + 768);

      const unsigned short* hc = hfrag + cur * 8192;
      bf16x8 af[16];
      #pragma unroll
      for (int kk = 0; kk < 16; ++kk)
        af[kk] = *(const bf16x8*)(hc + kk * 512 + lane * 8);

      // prefetch next flag (checked next iteration; latency hidden under MFMA)
      if (spin)
        fn = (t + 1 < T_STEPS)
                 ? __hip_atomic_load(&flags[t + 1], __ATOMIC_ACQUIRE, __HIP_MEMORY_SCOPE_AGENT)
                 : 1u;

      f32x4 acc0 = {0,0,0,0}, acc1 = {0,0,0,0}, acc2 = {0,0,0,0}, acc3 = {0,0,0,0};
      #pragma unroll
      for (int kk = 0; kk < 16; ++kk) {
        acc0 = MFMA16(wr0[kk], af[kk], acc0);
        acc1 = MFMA16(wr1[kk], af[kk], acc1);
      }

      unsigned short* hn = hfrag + (cur ^ 1) * 8192;
      auto tanhw = [&](int tau, const f32x4& a, const u32x2& xq) {
        float t0 = tanh_fast(a.x + bf16lo(xq.x));
        float t1 = tanh_fast(a.y + bf16hi(xq.x));
        float t2 = tanh_fast(a.z + bf16lo(xq.y));
        float t3 = tanh_fast(a.w + bf16hi(xq.y));
        u32x2 hv = {cvtpk(t0, t1), cvtpk(t2, t3)};
        // h[batch=c][n=wv*64+tau*16+g*4+j] -> hfrag[kk'][lane'][e0..e0+3]
        *(u32x2*)(hn + (kkw + (tau >> 1)) * 512 +
                  ((((tau & 1) << 1) + (g >> 1)) * 16 + c) * 8 + ((g & 1) << 2)) = hv;
      };

      tanhw(0, acc0, xq0);   // overlaps phase B's MFMAs
      #pragma unroll
      for (int kk = 0; kk < 16; ++kk) {
        acc2 = MFMA16(wr2[kk], af[kk], acc2);
        acc3 = MFMA16(wr3[kk], af[kk], acc3);
      }
      tanhw(1, acc1, xq1);
      tanhw(2, acc2, xq2);
      tanhw(3, acc3, xq3);

      __syncthreads();
      cur ^= 1;
    }

    // final h -> hT (f32)
    const unsigned short* hc = hfrag + cur * 8192;
    for (int i = tid; i < 16 * HID; i += 512) {
      const int b = i >> 9, n = i & 511;
      unsigned short v = hc[(n >> 5) * 512 + (((n >> 3) & 3) * 16 + b) * 8 + (n & 7)];
      hT[(size_t)(wg * 16 + b) * HID + n] = __uint_as_float((unsigned)v << 16);
    }
  } else {
    // ===================== K1 producer role =====================
    const int t = blockIdx.x - rnn_blocks;
    int* xi = (int*)SM;
    unsigned short (*xe)[328] = (unsigned short (*)[328])(SM + 256);
    if (tid < 64) xi[tid] = x[tid * T_STEPS + t];
    __syncthreads();
    {
      const int r = tid >> 3, q = tid & 7;       // 8 threads per emb row
      const float* src = emb + (size_t)xi[r] * EMB_D;
      for (int jp = q; jp < 150; jp += 8) {
        const int j = jp * 2;
        *(unsigned*)&xe[r][j] = cvtpk(src[j], src[j + 1]);
      }
      if (q == 6) { for (int j = 300; j < 314; j += 2) *(unsigned*)&xe[r][j] = 0; }
      if (q == 7) { for (int j = 314; j < 328; j += 2) *(unsigned*)&xe[r][j] = 0; }
    }
    __syncthreads();

    const int wv = tid >> 6, lane = tid & 63;
    const int c = lane & 15, g = lane >> 4;
    const f32x4 z4 = {0, 0, 0, 0};

    bf16x8 af[4][10];                       // B operand: col=batch a*16+c
    #pragma unroll
    for (int a = 0; a < 4; ++a) {
      #pragma unroll
      for (int kk = 0; kk < 10; ++kk)
        af[a][kk] = *(const bf16x8*)&xe[a * 16 + c][kk * 32 + g * 8];
    }

    #pragma unroll 1
    for (int nt4 = 0; nt4 < 4; ++nt4) {     // 8 waves x 4 tiles = 32 n-tiles
      const int nt = wv * 4 + nt4;
      const int n = nt * 16 + c;            // A row (n-dim)
      f32x4 a0 = z4, a1 = z4, a2 = z4, a3 = z4;
      #pragma unroll
      for (int kk = 0; kk < 10; ++kk) {
        const int k0 = kk * 32 + g * 8;
        f32x4 blo = (k0 < EMB_D) ? *(const f32x4*)(Wih + (size_t)n * EMB_D + k0) : z4;
        f32x4 bhi = (k0 + 4 < EMB_D) ? *(const f32x4*)(Wih + (size_t)n * EMB_D + k0 + 4) : z4;
        bf16x8 wf = pack8(blo, bhi);
        a0 = MFMA16(wf, af[0][kk], a0);
        a1 = MFMA16(wf, af[1][kk], a1);
        a2 = MFMA16(wf, af[2][kk], a2);
        a3 = MFMA16(wf, af[3][kk], a3);
      }
      const int n0 = nt * 16 + g * 4;
      f32x4 bias4 = *(const f32x4*)(bih + n0) + *(const f32x4*)(bhh + n0);
      #pragma unroll
      for (int a = 0; a < 4; ++a) {
        f32x4 o = ((a == 0) ? a0 : (a == 1) ? a1 : (a == 2) ? a2 : a3) + bias4;
        u32x2 pk = {cvtpk(o.x, o.y), cvtpk(o.z, o.w)};
        *(u32x2*)(xp + (((size_t)t * 4 + a) * 32 + nt) * 256 + lane * 4) = pk;
      }
    }
    if (flags) {
      __syncthreads();
      if (tid == 0) {
        __threadfence();
        __hip_atomic_store(&flags[t], 1u, __ATOMIC_RELEASE, __HIP_MEMORY_SCOPE_AGENT);
      }
    }
  }
}

// ---------------------------------------------------------------------------
// K3: out[b][c] = hT[b] . W_fc[c] + b_fc[c]
// ---------------------------------------------------------------------------
__global__ __launch_bounds__(256) void k3_head(
    const float* __restrict__ hT, const float* __restrict__ Wfc,
    const float* __restrict__ bfc, float* __restrict__ out) {
  __shared__ float hrow[HID];
  const int b = blockIdx.x, tid = threadIdx.x;
  hrow[tid] = hT[(size_t)b * HID + tid];
  hrow[tid + 256] = hT[(size_t)b * HID + tid + 256];
  __syncthreads();
  for (int cc = tid; cc < NCLS; cc += 256) {
    const f32x4* W4 = (const f32x4*)(Wfc + (size_t)cc * HID);
    float s0 = 0, s1 = 0, s2 = 0, s3 = 0;
    #pragma unroll 4
    for (int j = 0; j < HID / 4; ++j) {
      f32x4 w = W4[j];
      f32x4 h4 = *(const f32x4*)(hrow + j * 4);
      s0 += h4.x * w.x; s1 += h4.y * w.y; s2 += h4.z * w.z; s3 += h4.w * w.w;
    }
    out[(size_t)b * NCLS + cc] = bfc[cc] + s0 + s1 + s2 + s3;
  }
}

extern "C" void kernel_launch(void* const* d_in, const int* in_sizes, int n_in,
                              void* d_out, int out_size, void* d_ws, size_t ws_size,
                              hipStream_t stream) {
  (void)in_sizes; (void)n_in; (void)out_size;
  const int*   x   = (const int*)d_in[0];
  const float* emb = (const float*)d_in[1];
  const float* Wih = (const float*)d_in[2];
  const float* Whh = (const float*)d_in[3];
  const float* bih = (const float*)d_in[4];
  const float* bhh = (const float*)d_in[5];
  const float* Wfc = (const float*)d_in[6];
  const float* bfc = (const float*)d_in[7];
  float* out = (float*)d_out;

  // ws: xp 33,554,432 | hT 131,072 | wpack 524,288 | flags 2,048
  const size_t XP_B = (size_t)T_STEPS * HID * BATCH * 2;
  const size_t HT_B = (size_t)BATCH * HID * 4;
  const size_t WP_B = 524288;
  unsigned short* xp = (unsigned short*)d_ws;
  float* hT = (float*)((char*)d_ws + XP_B);
  unsigned short* wpack = (unsigned short*)((char*)d_ws + XP_B + HT_B);
  unsigned* flags = (unsigned*)((char*)d_ws + XP_B + HT_B + WP_B);
  const bool fused = ws_size >= XP_B + HT_B + WP_B + T_STEPS * sizeof(unsigned);

  k0_pack<<<128, 256, 0, stream>>>(Whh, wpack);
  if (fused) {
    // producers (blocks 4..515) + 4 RNN consumers in one launch; flag-synced
    k12_fused<<<4 + T_STEPS, 512, 0, stream>>>(x, emb, Wih, bih, bhh, xp, wpack,
                                               hT, flags, 4, 1);
  } else {
    k12_fused<<<T_STEPS, 512, 0, stream>>>(x, emb, Wih, bih, bhh, xp, wpack,
                                           hT, nullptr, 0, 0);
    k12_fused<<<4, 512, 0, stream>>>(x, emb, Wih, bih, bhh, xp, wpack,
                                     hT, nullptr, 4, 0);
  }
  k3_head<<<64, 256, 0, stream>>>(hT, Wfc, bfc, out);
}

// Round 8
// 1266.948 us; speedup vs baseline: 2.9205x; 2.9205x over previous
//
#include <hip/hip_runtime.h>
#include <hip/hip_bf16.h>

#define T_STEPS 512
#define HID 512
#define EMB_D 300
#define BATCH 64
#define NCLS 1000

typedef __attribute__((ext_vector_type(4))) float f32x4;
typedef __attribute__((ext_vector_type(8))) short bf16x8;
typedef __attribute__((ext_vector_type(4))) unsigned int u32x4;
typedef __attribute__((ext_vector_type(2))) unsigned int u32x2;

union FragU { u32x4 u; bf16x8 b; };

__device__ __forceinline__ unsigned cvtpk(float lo, float hi) {
  unsigned r;
  asm("v_cvt_pk_bf16_f32 %0, %1, %2" : "=v"(r) : "v"(lo), "v"(hi));
  return r;
}

__device__ __forceinline__ bf16x8 pack8(f32x4 lo, f32x4 hi) {
  FragU u;
  u.u = (u32x4){cvtpk(lo.x, lo.y), cvtpk(lo.z, lo.w), cvtpk(hi.x, hi.y), cvtpk(hi.z, hi.w)};
  return u.b;
}

// tanh(x) = 1 - 2/(e+1), e = 2^(2*log2e*x). e->0 gives -1, e->inf gives 1.
__device__ __forceinline__ float tanh_fast(float x) {
  float e = __builtin_amdgcn_exp2f(x * 2.8853900817779268f);
  return fmaf(-2.0f, __builtin_amdgcn_rcpf(e + 1.0f), 1.0f);
}

__device__ __forceinline__ float bf16lo(unsigned u) { return __uint_as_float(u << 16); }
__device__ __forceinline__ float bf16hi(unsigned u) { return __uint_as_float(u & 0xffff0000u); }

#define MFMA16(A, B, C) __builtin_amdgcn_mfma_f32_16x16x32_bf16(A, B, C, 0, 0, 0)

// ---------------------------------------------------------------------------
// K0: pack W_hh (f32) -> bf16 A-operand fragments.
// wpack[wv 8][tile 4][kk 16][lane 64][e 8] = Whh[wv*64+tile*16+(lane&15)][kk*32+(lane>>4)*8+e]
// ---------------------------------------------------------------------------
__global__ __launch_bounds__(256) void k0_pack(const float* __restrict__ Whh,
                                               unsigned short* __restrict__ wpack) {
  const int idx = blockIdx.x * 256 + threadIdx.x;  // 0..32767 lane-frags
  const int lane = idx & 63;
  const int kk = (idx >> 6) & 15;
  const int tw = (idx >> 10) & 3;
  const int wv = idx >> 12;
  const int c = lane & 15, g = lane >> 4;
  const int i = wv * 64 + tw * 16 + c;
  const int j = kk * 32 + g * 8;
  f32x4 lo = *(const f32x4*)(Whh + (size_t)i * HID + j);
  f32x4 hi = *(const f32x4*)(Whh + (size_t)i * HID + j + 4);
  *(bf16x8*)(wpack + (size_t)idx * 8) = pack8(lo, hi);
}

// ---------------------------------------------------------------------------
// K1 (round-5, measured-good): xp = emb[x] . W_ih^T + b_ih + b_hh, TILE-PACKED:
// xp[t][a 4][nt 32][lane 64][4 shorts] = 4 consecutive n (g*4..+3) for batch
// a*16+c. One block per t; emb rows staged to LDS bf16 once.
// ---------------------------------------------------------------------------
__global__ __launch_bounds__(256) void k1_embed_proj(
    const int* __restrict__ x, const float* __restrict__ emb,
    const float* __restrict__ Wih, const float* __restrict__ bih,
    const float* __restrict__ bhh, unsigned short* __restrict__ xp) {
  __shared__ unsigned short xe[64][328];
  __shared__ int xi[64];
  const int tid = threadIdx.x;
  const int t = blockIdx.x;
  if (tid < 64) xi[tid] = x[tid * T_STEPS + t];
  __syncthreads();
  {
    const int r = tid >> 2, q = tid & 3;
    const float* src = emb + (size_t)xi[r] * EMB_D;
    for (int jp = q; jp < 150; jp += 4) {
      const int j = jp * 2;
      *(unsigned*)&xe[r][j] = cvtpk(src[j], src[j + 1]);
    }
    if (q == 3) {
      #pragma unroll
      for (int j = 300; j < 328; j += 2) *(unsigned*)&xe[r][j] = 0;
    }
  }
  __syncthreads();

  const int wv = tid >> 6, lane = tid & 63;
  const int c = lane & 15, g = lane >> 4;
  const f32x4 z4 = {0, 0, 0, 0};

  bf16x8 af[4][10];
  #pragma unroll
  for (int a = 0; a < 4; ++a) {
    #pragma unroll
    for (int kk = 0; kk < 10; ++kk)
      af[a][kk] = *(const bf16x8*)&xe[a * 16 + c][kk * 32 + g * 8];
  }

  #pragma unroll 1
  for (int nt8 = 0; nt8 < 8; ++nt8) {
    const int nt = wv * 8 + nt8;
    const int n = nt * 16 + c;
    f32x4 a0 = z4, a1 = z4, a2 = z4, a3 = z4;
    #pragma unroll
    for (int kk = 0; kk < 10; ++kk) {
      const int k0 = kk * 32 + g * 8;
      f32x4 blo = (k0 < EMB_D) ? *(const f32x4*)(Wih + (size_t)n * EMB_D + k0) : z4;
      f32x4 bhi = (k0 + 4 < EMB_D) ? *(const f32x4*)(Wih + (size_t)n * EMB_D + k0 + 4) : z4;
      bf16x8 wf = pack8(blo, bhi);
      a0 = MFMA16(wf, af[0][kk], a0);
      a1 = MFMA16(wf, af[1][kk], a1);
      a2 = MFMA16(wf, af[2][kk], a2);
      a3 = MFMA16(wf, af[3][kk], a3);
    }
    const int n0 = nt * 16 + g * 4;
    f32x4 bias4 = *(const f32x4*)(bih + n0) + *(const f32x4*)(bhh + n0);
    #pragma unroll
    for (int a = 0; a < 4; ++a) {
      f32x4 o = ((a == 0) ? a0 : (a == 1) ? a1 : (a == 2) ? a2 : a3) + bias4;
      u32x2 pk = {cvtpk(o.x, o.y), cvtpk(o.z, o.w)};
      *(u32x2*)(xp + (((size_t)t * 4 + a) * 32 + nt) * 256 + lane * 4) = pk;
    }
  }
}

// ---------------------------------------------------------------------------
// K2 v4: persistent RNN, 4 WGs x 512 thr (8 waves). Round-5 register split
// (tiles 0,1,2 + tile3/kk0 -> AGPR via compiler; tile3/kk1..15 in LDS with
// rolling prefetch) + two proven round-7 features:
//  - h in FRAGMENT layout hfrag[2][kk 16][lane 64][e 8]: af reads are linear
//    lane*16B ds_read_b128 (no 8-way conflicts), writes are clean 8B.
//  - phase-split: MFMA(acc0,acc1) -> tanh0 -> MFMA(acc2,acc3) -> tanh1..3,
//    overlapping VALU tanh with the matrix pipe.
// ---------------------------------------------------------------------------
__global__ __launch_bounds__(512) void k2_rnn(
    const unsigned short* __restrict__ wpack,
    const unsigned short* __restrict__ xp, float* __restrict__ hT) {
  __shared__ unsigned short hfrag[2][16][64][8];  // 32,768 B
  __shared__ unsigned short wlds[8][15][512];     // 122,880 B

  const int tid = threadIdx.x;
  const int wv = tid >> 6, lane = tid & 63;
  const int c = lane & 15, g = lane >> 4;
  const int wg = blockIdx.x;                      // batch rows wg*16..+15

  // ---- weights: tiles 0,1,2 + tile3/kk0 to registers (AGPR), rest to LDS ----
  const unsigned short* wp = wpack + (size_t)wv * 32768 + (size_t)lane * 8;
  bf16x8 wr0[16], wr1[16], wr2[16], w30;
  #pragma unroll
  for (int kk = 0; kk < 16; ++kk) {
    wr0[kk] = *(const bf16x8*)(wp + (size_t)kk * 512);
    wr1[kk] = *(const bf16x8*)(wp + (size_t)(16 + kk) * 512);
    wr2[kk] = *(const bf16x8*)(wp + (size_t)(32 + kk) * 512);
  }
  w30 = *(const bf16x8*)(wp + (size_t)48 * 512);
  #pragma unroll
  for (int kk = 1; kk < 16; ++kk) {
    bf16x8 f = *(const bf16x8*)(wp + (size_t)(48 + kk) * 512);
    *(bf16x8*)&wlds[wv][kk - 1][lane * 8] = f;
  }

  for (int i = tid; i < 8192; i += 512) ((unsigned*)hfrag)[i] = 0;  // h0 = 0
  __syncthreads();

  // xp: element (t, a=wg, nt=wv*4+tau, lane) at ((t*4+a)*32+nt)*256 + lane*4
  const unsigned short* xpb = xp + (size_t)wg * 8192 + (size_t)wv * 1024 + (size_t)lane * 4;
  u32x2 xq0 = *(const u32x2*)(xpb);
  u32x2 xq1 = *(const u32x2*)(xpb + 256);
  u32x2 xq2 = *(const u32x2*)(xpb + 512);
  u32x2 xq3 = *(const u32x2*)(xpb + 768);

  const int kkw = wv * 2;
  int cur = 0;

  #pragma unroll 1
  for (int t = 0; t < T_STEPS; ++t) {
    const unsigned short* hc = &hfrag[cur][0][0][0];
    bf16x8 af[16];
    #pragma unroll
    for (int kk = 0; kk < 16; ++kk)
      af[kk] = *(const bf16x8*)(hc + kk * 512 + lane * 8);

    f32x4 acc0 = {0,0,0,0}, acc1 = {0,0,0,0}, acc2 = {0,0,0,0}, acc3 = {0,0,0,0};
    // Phase A: tiles 0,1 (register-resident)
    #pragma unroll
    for (int kk = 0; kk < 16; ++kk) {
      acc0 = MFMA16(wr0[kk], af[kk], acc0);
      acc1 = MFMA16(wr1[kk], af[kk], acc1);
    }

    unsigned short* hn = &hfrag[cur ^ 1][0][0][0];
    auto tanhw = [&](int tau, const f32x4& a, const u32x2& xq) {
      float t0 = tanh_fast(a.x + bf16lo(xq.x));
      float t1 = tanh_fast(a.y + bf16hi(xq.x));
      float t2 = tanh_fast(a.z + bf16lo(xq.y));
      float t3 = tanh_fast(a.w + bf16hi(xq.y));
      u32x2 hv = {cvtpk(t0, t1), cvtpk(t2, t3)};
      // h[batch=c][n=wv*64+tau*16+g*4+j] -> hfrag[n>>5][((n>>3)&3)*16+c][n&7]
      *(u32x2*)(hn + (kkw + (tau >> 1)) * 512 +
                ((((tau & 1) << 1) + (g >> 1)) * 16 + c) * 8 + ((g & 1) << 2)) = hv;
    };

    tanhw(0, acc0, xq0);   // VALU overlaps phase B's MFMAs

    // Phase B: tile 2 (regs) + tile 3 (kk0 reg, kk1..15 LDS rolling prefetch)
    bf16x8 w3c = w30;
    #pragma unroll
    for (int kk = 0; kk < 16; ++kk) {
      bf16x8 w3n = w3c;
      if (kk < 15) w3n = *(const bf16x8*)&wlds[wv][kk][lane * 8];
      acc2 = MFMA16(wr2[kk], af[kk], acc2);
      acc3 = MFMA16(w3c, af[kk], acc3);
      w3c = w3n;
    }
    tanhw(1, acc1, xq1);
    tanhw(2, acc2, xq2);
    tanhw(3, acc3, xq3);

    // prefetch next step's xq before the barrier (completes during sync)
    if (t + 1 < T_STEPS) {
      const unsigned short* nx = xpb + (size_t)(t + 1) * 32768;
      xq0 = *(const u32x2*)(nx);
      xq1 = *(const u32x2*)(nx + 256);
      xq2 = *(const u32x2*)(nx + 512);
      xq3 = *(const u32x2*)(nx + 768);
    }
    __syncthreads();
    cur ^= 1;
  }

  // final h -> hT (f32): h[b][n] at hfrag[cur][n>>5][((n>>3)&3)*16+b][n&7]
  const unsigned short* hc = &hfrag[cur][0][0][0];
  for (int i = tid; i < 16 * HID; i += 512) {
    const int b = i >> 9, n = i & 511;
    unsigned short v = hc[(n >> 5) * 512 + (((n >> 3) & 3) * 16 + b) * 8 + (n & 7)];
    hT[(size_t)(wg * 16 + b) * HID + n] = __uint_as_float((unsigned)v << 16);
  }
}

// ---------------------------------------------------------------------------
// K3: out[b][c] = hT[b] . W_fc[c] + b_fc[c]
// ---------------------------------------------------------------------------
__global__ __launch_bounds__(256) void k3_head(
    const float* __restrict__ hT, const float* __restrict__ Wfc,
    const float* __restrict__ bfc, float* __restrict__ out) {
  __shared__ float hrow[HID];
  const int b = blockIdx.x, tid = threadIdx.x;
  hrow[tid] = hT[(size_t)b * HID + tid];
  hrow[tid + 256] = hT[(size_t)b * HID + tid + 256];
  __syncthreads();
  for (int cc = tid; cc < NCLS; cc += 256) {
    const f32x4* W4 = (const f32x4*)(Wfc + (size_t)cc * HID);
    float s0 = 0, s1 = 0, s2 = 0, s3 = 0;
    #pragma unroll 4
    for (int j = 0; j < HID / 4; ++j) {
      f32x4 w = W4[j];
      f32x4 h4 = *(const f32x4*)(hrow + j * 4);
      s0 += h4.x * w.x; s1 += h4.y * w.y; s2 += h4.z * w.z; s3 += h4.w * w.w;
    }
    out[(size_t)b * NCLS + cc] = bfc[cc] + s0 + s1 + s2 + s3;
  }
}

extern "C" void kernel_launch(void* const* d_in, const int* in_sizes, int n_in,
                              void* d_out, int out_size, void* d_ws, size_t ws_size,
                              hipStream_t stream) {
  (void)in_sizes; (void)n_in; (void)out_size; (void)ws_size;
  const int*   x   = (const int*)d_in[0];
  const float* emb = (const float*)d_in[1];
  const float* Wih = (const float*)d_in[2];
  const float* Whh = (const float*)d_in[3];
  const float* bih = (const float*)d_in[4];
  const float* bhh = (const float*)d_in[5];
  const float* Wfc = (const float*)d_in[6];
  const float* bfc = (const float*)d_in[7];
  float* out = (float*)d_out;

  // ws: xp tile-packed 33,554,432 B | hT f32 131,072 B | wpack 524,288 B
  const size_t XP_B = (size_t)T_STEPS * HID * BATCH * 2;
  const size_t HT_B = (size_t)BATCH * HID * 4;
  unsigned short* xp = (unsigned short*)d_ws;
  float* hT = (float*)((char*)d_ws + XP_B);
  unsigned short* wpack = (unsigned short*)((char*)d_ws + XP_B + HT_B);

  k0_pack<<<128, 256, 0, stream>>>(Whh, wpack);
  k1_embed_proj<<<512, 256, 0, stream>>>(x, emb, Wih, bih, bhh, xp);
  k2_rnn<<<4, 512, 0, stream>>>(wpack, xp, hT);
  k3_head<<<64, 256, 0, stream>>>(hT, Wfc, bfc, out);
}